// Round 1
// baseline (233.003 us; speedup 1.0000x reference)
//
#include <hip/hip_runtime.h>

#define OBS_LEN 8
#define PRED_LEN 12
#define TILE_B 32
#define NTHREADS 256

typedef __attribute__((ext_vector_type(8))) short short8;  // 8 bf16
typedef __attribute__((ext_vector_type(4))) float floatx4;
typedef __attribute__((ext_vector_type(2))) float floatx2;
typedef __attribute__((ext_vector_type(2))) unsigned int u32x2;
typedef unsigned short u16;
typedef unsigned int u32;

#define L2E 1.442695040888963f

__device__ __forceinline__ u16 f2bf(float f) {
  __bf16 b = (__bf16)f;
  return __builtin_bit_cast(u16, b);
}
__device__ __forceinline__ float bf2f(u16 h) {
  return __builtin_bit_cast(float, ((u32)h) << 16);
}
__device__ __forceinline__ float rndbf(float f) { return (float)(__bf16)f; }

#if __has_builtin(__builtin_amdgcn_exp2f)
__device__ __forceinline__ float fexp2_(float x) { return __builtin_amdgcn_exp2f(x); }
#else
__device__ __forceinline__ float fexp2_(float x) { return exp2f(x); }
#endif
__device__ __forceinline__ floatx2 exp2v(floatx2 x) {
  floatx2 r;
  r.x = fexp2_(x.x);
  r.y = fexp2_(x.y);
  return r;
}
#if __has_builtin(__builtin_amdgcn_rcpf)
__device__ __forceinline__ floatx2 rcp2(floatx2 x) {  // raw v_rcp ~1ulp
  floatx2 r;
  r.x = __builtin_amdgcn_rcpf(x.x);
  r.y = __builtin_amdgcn_rcpf(x.y);
  return r;
}
#else
__device__ __forceinline__ floatx2 rcp2(floatx2 x) {
  return floatx2{1.0f / x.x, 1.0f / x.y};
}
#endif

__device__ __forceinline__ floatx4 mfma_bf(short8 a, short8 b, floatx4 c) {
  return __builtin_amdgcn_mfma_f32_16x16x32_bf16(a, b, c, 0, 0, 0);
}

// XOR-swizzled LDS row layout: sample row = 64 u16 (128B, bank-aligned);
// element u lives in 16B block (u>>3) ^ (s&7).
__device__ __forceinline__ int swz(int s, int b) {
  return s * 64 + ((b ^ (s & 7)) * 8);
}

// A-operand fragments (A[m=lane&15][k=quad*8+j]) for this wave's 4 gate tiles
// (gate = t*64 + u0 + l16), weights rounded to bf16 = the ref's operand rounding.
__device__ __forceinline__ void load_afrags(const float* __restrict__ W,
                                            short8 (&af)[4][2],
                                            int u0, int q, int l16) {
#pragma unroll
  for (int t = 0; t < 4; ++t)
#pragma unroll
    for (int kf = 0; kf < 2; ++kf) {
      const float* src = W + (t * 64 + u0 + l16) * 64 + kf * 32 + q * 8;
      const floatx4 w0 = *(const floatx4*)src;
      const floatx4 w1 = *(const floatx4*)(src + 4);
      short8 a;
#pragma unroll
      for (int j = 0; j < 4; ++j) {
        a[j] = (short)f2bf(w0[j]);
        a[j + 4] = (short)f2bf(w1[j]);
      }
      af[t][kf] = a;
    }
}

// Folded decoder weights: W_eff[g,u] = W_hh[g,u] + A0[g]*h2p[0,u] + A1[g]*h2p[1,u]
// (rank-2 update, f32 math, ONE bf16 rounding at the end).
__device__ __forceinline__ void load_afrags_eff(const float* __restrict__ Whh,
                                                const float* __restrict__ aS0,
                                                const float* __restrict__ aS1,
                                                const float* __restrict__ hw0,
                                                const float* __restrict__ hw1,
                                                short8 (&af)[4][2],
                                                int u0, int q, int l16) {
#pragma unroll
  for (int t = 0; t < 4; ++t) {
    const int g = t * 64 + u0 + l16;
    const float a0 = aS0[g], a1 = aS1[g];
#pragma unroll
    for (int kf = 0; kf < 2; ++kf) {
      const int u = kf * 32 + q * 8;
      const float* src = Whh + g * 64 + u;
      const floatx4 w0 = *(const floatx4*)src;
      const floatx4 w1 = *(const floatx4*)(src + 4);
      const floatx4 p00 = *(const floatx4*)(hw0 + u);
      const floatx4 p01 = *(const floatx4*)(hw0 + u + 4);
      const floatx4 p10 = *(const floatx4*)(hw1 + u);
      const floatx4 p11 = *(const floatx4*)(hw1 + u + 4);
      short8 a;
#pragma unroll
      for (int j = 0; j < 4; ++j) {
        a[j] = (short)f2bf(w0[j] + a0 * p00[j] + a1 * p10[j]);
        a[j + 4] = (short)f2bf(w1[j] + a0 * p01[j] + a1 * p11[j]);
      }
      af[t][kf] = a;
    }
  }
}

// Gate nonlinearity + swizzled h write for one 16x16 tile (verbatim math from
// the proven kernel; c2 = running cell state for this n-tile).
__device__ __forceinline__ void nonlin_store(const floatx4 (&acc)[4],
                                             floatx2 (&c2)[2],
                                             u16* __restrict__ wrh,
                                             int s, int q, int wv) {
  const int sw = s & 7;
  u32 hpk[2];
#pragma unroll
  for (int p = 0; p < 2; ++p) {
    const floatx2 iv = {acc[0][2 * p], acc[0][2 * p + 1]};
    const floatx2 fv = {acc[1][2 * p], acc[1][2 * p + 1]};
    const floatx2 gv = {acc[2][2 * p], acc[2][2 * p + 1]};
    const floatx2 ov = {acc[3][2 * p], acc[3][2 * p + 1]};
    const floatx2 ei = exp2v(iv * -L2E);
    const floatx2 ef = exp2v(fv * -L2E);
    const floatx2 eg = exp2v(gv * (2.0f * L2E));
    const floatx2 eo = exp2v(ov * -L2E);
    const floatx2 A = ei + 1.0f;   // 1/sig(i)
    const floatx2 F = ef + 1.0f;   // 1/sig(f)
    const floatx2 Bg = eg + 1.0f;  // tanh(g) = (eg-1)/Bg
    const floatx2 P = A * Bg;
    const floatx2 num = c2[p] * P + (eg - 1.0f) * F;
    const floatx2 cn = num * rcp2(F * P);
    c2[p] = cn;
    const floatx2 ec = exp2v(cn * (2.0f * L2E));
    const floatx2 h = (ec - 1.0f) * rcp2((eo + 1.0f) * (ec + 1.0f));
    hpk[p] = (u32)f2bf(h.x) | ((u32)f2bf(h.y) << 16);
  }
  *(u32x2*)(wrh + s * 64 + (((wv * 2 + (q >> 1)) ^ sw) * 8) + (q & 1) * 4) =
      u32x2{hpk[0], hpk[1]};
}

// One cell step for this wave's 16-gate slice x 32 samples (encoder + dec step 0).
__device__ __forceinline__ void cell_step(const u16* __restrict__ rdh,
                                          const u16* __restrict__ rdx,
                                          u16* __restrict__ wrh,
                                          const short8 (&afh)[4][2],
                                          const short8 (&afx)[4][2],
                                          const float* __restrict__ biasrow,
                                          floatx2 (&c)[2][2],
                                          int q, int l16, int wv, int u0) {
#pragma unroll
  for (int n = 0; n < 2; ++n) {
    const int s = n * 16 + l16;
    const int sw = s & 7;
    const u16* hr = rdh + s * 64;
    const u16* xr = rdx + s * 64;
    const short8 hb0 = *(const short8*)(hr + ((q ^ sw) * 8));
    const short8 hb1 = *(const short8*)(hr + (((q + 4) ^ sw) * 8));
    const short8 xb0 = *(const short8*)(xr + ((q ^ sw) * 8));
    const short8 xb1 = *(const short8*)(xr + (((q + 4) ^ sw) * 8));
    floatx4 acc[4];
#pragma unroll
    for (int t = 0; t < 4; ++t) {
      const floatx4 bias = *(const floatx4*)(biasrow + t * 64 + u0 + q * 4);
      acc[t] = mfma_bf(afh[t][0], hb0, bias);
    }
#pragma unroll
    for (int t = 0; t < 4; ++t) acc[t] = mfma_bf(afx[t][0], xb0, acc[t]);
#pragma unroll
    for (int t = 0; t < 4; ++t) acc[t] = mfma_bf(afh[t][1], hb1, acc[t]);
#pragma unroll
    for (int t = 0; t < 4; ++t) acc[t] = mfma_bf(afx[t][1], xb1, acc[t]);
    nonlin_store(acc, c[n], wrh, s, q, wv);
  }
}

// Folded decoder step (j>=1): gates = h @ W_eff^T + b_eff (K=64, 16 MFMAs),
// rel_{j-1} computed in-register from the same h B-frags (f32 h2p weights)
// and stored coalesced from the q==0 lanes. ONE barrier per step (caller).
__device__ __forceinline__ void dec_step_folded(
    const u16* __restrict__ rdh, u16* __restrict__ wrh,
    const short8 (&af)[4][2], const float* __restrict__ biasrow,
    const float* __restrict__ hw0, const float* __restrict__ hw1,
    float b2p0, float b2p1, float* __restrict__ outp, long S0,
    floatx2 (&c)[2][2], int q, int l16, int wv, int u0) {
  short8 hb0[2], hb1[2];
#pragma unroll
  for (int n = 0; n < 2; ++n) {
    const int s = n * 16 + l16, sw = s & 7;
    const u16* hr = rdh + s * 64;
    hb0[n] = *(const short8*)(hr + ((q ^ sw) * 8));
    hb1[n] = *(const short8*)(hr + (((q + 4) ^ sw) * 8));
  }
  floatx4 acc[2][4];
#pragma unroll
  for (int t = 0; t < 4; ++t) {
    const floatx4 bias = *(const floatx4*)(biasrow + t * 64 + u0 + q * 4);
    acc[0][t] = mfma_bf(af[t][0], hb0[0], bias);
    acc[1][t] = mfma_bf(af[t][0], hb0[1], bias);
  }
#pragma unroll
  for (int t = 0; t < 4; ++t) {
    acc[0][t] = mfma_bf(af[t][1], hb1[0], acc[0][t]);
    acc[1][t] = mfma_bf(af[t][1], hb1[1], acc[1][t]);
  }
  // rel dot (VALU) overlaps the MFMA latency above; each lane owns 16 h-units.
  floatx2 d[2] = {floatx2{0.f, 0.f}, floatx2{0.f, 0.f}};
#pragma unroll
  for (int hf = 0; hf < 2; ++hf) {
    const int ub = hf * 32 + q * 8;
    const floatx4 wa0 = *(const floatx4*)(hw0 + ub);
    const floatx4 wa1 = *(const floatx4*)(hw0 + ub + 4);
    const floatx4 wb0 = *(const floatx4*)(hw1 + ub);
    const floatx4 wb1 = *(const floatx4*)(hw1 + ub + 4);
#pragma unroll
    for (int n = 0; n < 2; ++n) {
      const short8 hb = hf ? hb1[n] : hb0[n];
#pragma unroll
      for (int j = 0; j < 4; ++j) {
        const float h0 = bf2f((u16)hb[j]);
        const float h1 = bf2f((u16)hb[j + 4]);
        d[n].x += wa0[j] * h0 + wa1[j] * h1;
        d[n].y += wb0[j] * h0 + wb1[j] * h1;
      }
    }
  }
#pragma unroll
  for (int n = 0; n < 2; ++n) {
    d[n].x += __shfl_xor(d[n].x, 16);
    d[n].x += __shfl_xor(d[n].x, 32);
    d[n].y += __shfl_xor(d[n].y, 16);
    d[n].y += __shfl_xor(d[n].y, 32);
  }
  if (q == 0) {
#pragma unroll
    for (int n = 0; n < 2; ++n)
      *(floatx2*)(outp + (S0 + n * 16 + l16) * 2) =
          floatx2{d[n].x + b2p0, d[n].y + b2p1};
  }
#pragma unroll
  for (int n = 0; n < 2; ++n)
    nonlin_store(acc[n], c[n], wrh, n * 16 + l16, q, wv);
}

// Trailing rel_11 from h_12 (dot + shuffle + store only).
__device__ __forceinline__ void rel_only(const u16* __restrict__ rdh,
                                         const float* __restrict__ hw0,
                                         const float* __restrict__ hw1,
                                         float b2p0, float b2p1,
                                         float* __restrict__ outp, long S0,
                                         int q, int l16) {
  floatx2 d[2] = {floatx2{0.f, 0.f}, floatx2{0.f, 0.f}};
#pragma unroll
  for (int n = 0; n < 2; ++n) {
    const int s = n * 16 + l16, sw = s & 7;
    const u16* hr = rdh + s * 64;
    const short8 hb0 = *(const short8*)(hr + ((q ^ sw) * 8));
    const short8 hb1 = *(const short8*)(hr + (((q + 4) ^ sw) * 8));
#pragma unroll
    for (int hf = 0; hf < 2; ++hf) {
      const int ub = hf * 32 + q * 8;
      const floatx4 wa0 = *(const floatx4*)(hw0 + ub);
      const floatx4 wa1 = *(const floatx4*)(hw0 + ub + 4);
      const floatx4 wb0 = *(const floatx4*)(hw1 + ub);
      const floatx4 wb1 = *(const floatx4*)(hw1 + ub + 4);
      const short8 hb = hf ? hb1 : hb0;
#pragma unroll
      for (int j = 0; j < 4; ++j) {
        const float h0 = bf2f((u16)hb[j]);
        const float h1 = bf2f((u16)hb[j + 4]);
        d[n].x += wa0[j] * h0 + wa1[j] * h1;
        d[n].y += wb0[j] * h0 + wb1[j] * h1;
      }
    }
  }
#pragma unroll
  for (int n = 0; n < 2; ++n) {
    d[n].x += __shfl_xor(d[n].x, 16);
    d[n].x += __shfl_xor(d[n].x, 32);
    d[n].y += __shfl_xor(d[n].y, 16);
    d[n].y += __shfl_xor(d[n].y, 32);
  }
  if (q == 0) {
#pragma unroll
    for (int n = 0; n < 2; ++n)
      *(floatx2*)(outp + (S0 + n * 16 + l16) * 2) =
          floatx2{d[n].x + b2p0, d[n].y + b2p1};
  }
}

// x[s][e] = bf16( rb@bf16(emb_w)^T + emb_b ); used by encoder + dec step 0 only.
__device__ __forceinline__ void xgen8(float rb0, float rb1,
                                      const float* __restrict__ ew0,
                                      const float* __restrict__ ew1,
                                      const float* __restrict__ eb,
                                      u16* __restrict__ xw, int s8, int p8) {
  short8 v;
#pragma unroll
  for (int j = 0; j < 8; ++j) {
    const int e = p8 * 8 + j;
    v[j] = (short)f2bf(rb0 * ew0[e] + (rb1 * ew1[e] + eb[e]));
  }
  *(short8*)(xw + swz(s8, p8)) = v;
}

// (256,3): 168 = 84 arch + 84 accum. MFMA-only data (A-frags, acc) in accum
// half; VALU-touched state must fit 84 arch regs. Decoder steps 1..11 use the
// algebraic fold x_j = lin(h_j): gates = h @ W_eff^T + b_eff where
// W_eff = W_hh + A0⊗h2p[0] + A1⊗h2p[1], A_r = W_ih@emb[:,r] (rank-2).
// This halves decoder MFMA (K=64), kills xS/areldot/xgen8 traffic there, and
// drops to ONE barrier per decoder step.
__global__ void __launch_bounds__(NTHREADS, 3)
lstm_kernel(const float* __restrict__ obs_rel,
            const float* __restrict__ enc_emb_w, const float* __restrict__ enc_emb_b,
            const float* __restrict__ enc_w_ih, const float* __restrict__ enc_w_hh,
            const float* __restrict__ enc_b_ih, const float* __restrict__ enc_b_hh,
            const float* __restrict__ dec_emb_w, const float* __restrict__ dec_emb_b,
            const float* __restrict__ dec_w_ih, const float* __restrict__ dec_w_hh,
            const float* __restrict__ dec_b_ih, const float* __restrict__ dec_b_hh,
            const float* __restrict__ h2p_w, const float* __restrict__ h2p_b,
            float* __restrict__ out, int batch) {
  __shared__ __align__(16) u16 hS[2][TILE_B * 64];
  __shared__ __align__(16) u16 xS[2][TILE_B * 64];
  __shared__ __align__(16) float posS[OBS_LEN][TILE_B * 2];
  __shared__ __align__(16) float biasS[3][256];  // enc, dec, dec-folded (f32)
  __shared__ float ew0e[64], ew1e[64], ebe[64];
  __shared__ float ew0d[64], ew1d[64], ebd[64];
  __shared__ __align__(16) float aS0[256], aS1[256];   // A_r[g] rank-2 factors
  __shared__ __align__(16) float hw0S[64], hw1S[64];   // h2p_w rows, f32 (unrounded)

  const int tid = threadIdx.x;
  const int wv = tid >> 6, lane = tid & 63;
  const int q = lane >> 4, l16 = lane & 15;
  const int u0 = wv << 4;
  const int s8 = tid >> 3, p8 = tid & 7;
  const long S0 = (long)blockIdx.x * TILE_B;

  if (tid < 128) {  // stage all 8 encoder-step position rows (coalesced)
    const int t = tid >> 4, i = tid & 15;
    *(floatx4*)&posS[t][i * 4] =
        *(const floatx4*)(obs_rel + (long)t * batch * 2 + S0 * 2 + i * 4);
  }
  if (tid < 64) {  // emb tables: weights bf16-rounded (operands), biases f32
    ew0e[tid] = rndbf(enc_emb_w[tid * 2]);
    ew1e[tid] = rndbf(enc_emb_w[tid * 2 + 1]);
    ebe[tid] = enc_emb_b[tid];
    ew0d[tid] = rndbf(dec_emb_w[tid * 2]);
    ew1d[tid] = rndbf(dec_emb_w[tid * 2 + 1]);
    ebd[tid] = dec_emb_b[tid];
    hw0S[tid] = h2p_w[tid];        // f32: rel output + W_eff build
    hw1S[tid] = h2p_w[64 + tid];
  }
  biasS[0][tid] = enc_b_ih[tid] + enc_b_hh[tid];
  {
    // Rank-2 fold factors for gate row g = tid (once per block, f32):
    // A_r[g] = sum_e W_ih[g,e]*emb_w[e,r];  B0[g] = sum_e W_ih[g,e]*emb_b[e]
    float A0 = 0.f, A1 = 0.f, B0 = 0.f;
    const float* wr = dec_w_ih + tid * 64;
#pragma unroll
    for (int e4 = 0; e4 < 16; ++e4) {
      const floatx4 w = *(const floatx4*)(wr + e4 * 4);
      const floatx4 m0 = *(const floatx4*)(dec_emb_w + e4 * 8);      // e0,e1 pairs
      const floatx4 m1 = *(const floatx4*)(dec_emb_w + e4 * 8 + 4);  // e2,e3 pairs
      const floatx4 bb = *(const floatx4*)(dec_emb_b + e4 * 4);
      A0 += w[0] * m0[0] + w[1] * m0[2] + w[2] * m1[0] + w[3] * m1[2];
      A1 += w[0] * m0[1] + w[1] * m0[3] + w[2] * m1[1] + w[3] * m1[3];
      B0 += w[0] * bb[0] + w[1] * bb[1] + w[2] * bb[2] + w[3] * bb[3];
    }
    aS0[tid] = A0;
    aS1[tid] = A1;
    const float db = dec_b_ih[tid] + dec_b_hh[tid];
    biasS[1][tid] = db;  // dec step 0 (unfolded)
    biasS[2][tid] = db + B0 + A0 * h2p_b[0] + A1 * h2p_b[1];  // folded steps
  }
  for (int i = tid; i < TILE_B * 64 / 2; i += NTHREADS) ((u32*)&hS[0][0])[i] = 0;

  short8 afh[4][2], afx[4][2];
  floatx2 c[2][2];
  load_afrags(enc_w_hh, afh, u0, q, l16);
  load_afrags(enc_w_ih, afx, u0, q, l16);
  c[0][0] = c[0][1] = c[1][0] = c[1][1] = floatx2{0.f, 0.f};
  const float b2p0 = h2p_b[0], b2p1 = h2p_b[1];
  __syncthreads();  // posS + tables + bias + fold factors + h0 visible
  {
    const floatx2 rr = *(const floatx2*)(&posS[0][s8 * 2]);
    xgen8(rndbf(rr.x), rndbf(rr.y), ew0e, ew1e, ebe, xS[0], s8, p8);
  }
  __syncthreads();  // x(0) visible

  int pb = 0;
#pragma unroll 1
  for (int t = 0; t < OBS_LEN; ++t) {
    // produce x(t+1) into the other buffer (h-independent, overlaps MFMA);
    // t==7 produces the decoder step-0 input with dec tables into xS[0]
    const int tn = t + 1;
    const floatx2 rr = *(const floatx2*)(&posS[(tn < 8) ? tn : 7][s8 * 2]);
    if (tn < 8)
      xgen8(rndbf(rr.x), rndbf(rr.y), ew0e, ew1e, ebe, xS[tn & 1], s8, p8);
    else
      xgen8(rndbf(rr.x), rndbf(rr.y), ew0d, ew1d, ebd, xS[0], s8, p8);
    cell_step(hS[pb], xS[t & 1], hS[pb ^ 1], afh, afx, &biasS[0][0], c,
              q, l16, wv, u0);
    __syncthreads();
    pb ^= 1;
  }

  // ---- decoder step 0 (x from last_pos, unfolded), c reset to 0
  load_afrags(dec_w_hh, afh, u0, q, l16);
  load_afrags(dec_w_ih, afx, u0, q, l16);
  c[0][0] = c[0][1] = c[1][0] = c[1][1] = floatx2{0.f, 0.f};
  cell_step(hS[pb], xS[0], hS[pb ^ 1], afh, afx, &biasS[1][0], c,
            q, l16, wv, u0);
  // rebuild afh as W_eff fragments (afx is dead from here on)
  load_afrags_eff(dec_w_hh, aS0, aS1, hw0S, hw1S, afh, u0, q, l16);
  __syncthreads();
  pb ^= 1;

  // ---- folded decoder steps 1..11: one barrier each; rel_{j-1} emitted
  //      in-register off the critical path
#pragma unroll 1
  for (int j = 1; j < PRED_LEN; ++j) {
    dec_step_folded(hS[pb], hS[pb ^ 1], afh, &biasS[2][0], hw0S, hw1S,
                    b2p0, b2p1, out + (long)(j - 1) * batch * 2, S0, c,
                    q, l16, wv, u0);
    __syncthreads();  // h_{j+1} ready; hS[pb] reads done before next overwrite
    pb ^= 1;
  }

  // ---- trailing output: rel_pos[11] from h_12
  rel_only(hS[pb], hw0S, hw1S, b2p0, b2p1,
           out + (long)(PRED_LEN - 1) * batch * 2, S0, q, l16);
}

extern "C" void kernel_launch(void* const* d_in, const int* in_sizes, int n_in,
                              void* d_out, int out_size, void* d_ws, size_t ws_size,
                              hipStream_t stream) {
  const float* obs_rel = (const float*)d_in[1];
  const int batch = in_sizes[1] / (OBS_LEN * 2);  // 65536

  const int blocks = batch / TILE_B;  // 2048
  hipLaunchKernelGGL(lstm_kernel, dim3(blocks), dim3(NTHREADS), 0, stream,
                     obs_rel,
                     (const float*)d_in[2], (const float*)d_in[3],
                     (const float*)d_in[4], (const float*)d_in[5],
                     (const float*)d_in[6], (const float*)d_in[7],
                     (const float*)d_in[8], (const float*)d_in[9],
                     (const float*)d_in[10], (const float*)d_in[11],
                     (const float*)d_in[12], (const float*)d_in[13],
                     (const float*)d_in[14], (const float*)d_in[15],
                     (float*)d_out, batch);
}

// Round 3
// 218.532 us; speedup vs baseline: 1.0662x; 1.0662x over previous
//
#include <hip/hip_runtime.h>

#define OBS_LEN 8
#define PRED_LEN 12
#define TILE_B 32
#define NTHREADS 256

typedef __attribute__((ext_vector_type(8))) short short8;  // 8 bf16
typedef __attribute__((ext_vector_type(4))) float floatx4;
typedef __attribute__((ext_vector_type(2))) float floatx2;
typedef __attribute__((ext_vector_type(2))) unsigned int u32x2;
typedef unsigned short u16;
typedef unsigned int u32;

#define L2E 1.442695040888963f

__device__ __forceinline__ u16 f2bf(float f) {
  __bf16 b = (__bf16)f;
  return __builtin_bit_cast(u16, b);
}
__device__ __forceinline__ float bf2f(u16 h) {
  return __builtin_bit_cast(float, ((u32)h) << 16);
}
__device__ __forceinline__ float rndbf(float f) { return (float)(__bf16)f; }

#if __has_builtin(__builtin_amdgcn_exp2f)
__device__ __forceinline__ float fexp2_(float x) { return __builtin_amdgcn_exp2f(x); }
#else
__device__ __forceinline__ float fexp2_(float x) { return exp2f(x); }
#endif
__device__ __forceinline__ floatx2 exp2v(floatx2 x) {
  floatx2 r;
  r.x = fexp2_(x.x);
  r.y = fexp2_(x.y);
  return r;
}
#if __has_builtin(__builtin_amdgcn_rcpf)
__device__ __forceinline__ floatx2 rcp2(floatx2 x) {  // raw v_rcp ~1ulp
  floatx2 r;
  r.x = __builtin_amdgcn_rcpf(x.x);
  r.y = __builtin_amdgcn_rcpf(x.y);
  return r;
}
#else
__device__ __forceinline__ floatx2 rcp2(floatx2 x) {
  return floatx2{1.0f / x.x, 1.0f / x.y};
}
#endif

__device__ __forceinline__ floatx4 mfma_bf(short8 a, short8 b, floatx4 c) {
  return __builtin_amdgcn_mfma_f32_16x16x32_bf16(a, b, c, 0, 0, 0);
}

// XOR-swizzled LDS row layout: sample row = 64 u16 (128B, bank-aligned);
// element u lives in 16B block (u>>3) ^ (s&7).
__device__ __forceinline__ int swz(int s, int b) {
  return s * 64 + ((b ^ (s & 7)) * 8);
}

// A-operand fragments (A[m=lane&15][k=quad*8+j]) for this wave's 4 gate tiles
// (gate = t*64 + u0 + l16), weights rounded to bf16 = the ref's operand rounding.
__device__ __forceinline__ void load_afrags(const float* __restrict__ W,
                                            short8 (&af)[4][2],
                                            int u0, int q, int l16) {
#pragma unroll
  for (int t = 0; t < 4; ++t)
#pragma unroll
    for (int kf = 0; kf < 2; ++kf) {
      const float* src = W + (t * 64 + u0 + l16) * 64 + kf * 32 + q * 8;
      const floatx4 w0 = *(const floatx4*)src;
      const floatx4 w1 = *(const floatx4*)(src + 4);
      short8 a;
#pragma unroll
      for (int j = 0; j < 4; ++j) {
        a[j] = (short)f2bf(w0[j]);
        a[j + 4] = (short)f2bf(w1[j]);
      }
      af[t][kf] = a;
    }
}

// Folded decoder weights: W_eff[g,u] = W_hh[g,u] + A0[g]*h2p[0,u] + A1[g]*h2p[1,u]
// (rank-2 update, f32 math, ONE bf16 rounding at the end).
__device__ __forceinline__ void load_afrags_eff(const float* __restrict__ Whh,
                                                const float* __restrict__ aS0,
                                                const float* __restrict__ aS1,
                                                const float* __restrict__ hw0,
                                                const float* __restrict__ hw1,
                                                short8 (&af)[4][2],
                                                int u0, int q, int l16) {
#pragma unroll
  for (int t = 0; t < 4; ++t) {
    const int g = t * 64 + u0 + l16;
    const float a0 = aS0[g], a1 = aS1[g];
#pragma unroll
    for (int kf = 0; kf < 2; ++kf) {
      const int u = kf * 32 + q * 8;
      const float* src = Whh + g * 64 + u;
      const floatx4 w0 = *(const floatx4*)src;
      const floatx4 w1 = *(const floatx4*)(src + 4);
      const floatx4 p00 = *(const floatx4*)(hw0 + u);
      const floatx4 p01 = *(const floatx4*)(hw0 + u + 4);
      const floatx4 p10 = *(const floatx4*)(hw1 + u);
      const floatx4 p11 = *(const floatx4*)(hw1 + u + 4);
      short8 a;
#pragma unroll
      for (int j = 0; j < 4; ++j) {
        a[j] = (short)f2bf(w0[j] + a0 * p00[j] + a1 * p10[j]);
        a[j + 4] = (short)f2bf(w1[j] + a0 * p01[j] + a1 * p11[j]);
      }
      af[t][kf] = a;
    }
  }
}

// Gate nonlinearity + swizzled h write for one 16x16 tile (verbatim math from
// the proven kernel; c2 = running cell state for this n-tile).
__device__ __forceinline__ void nonlin_store(const floatx4 (&acc)[4],
                                             floatx2 (&c2)[2],
                                             u16* __restrict__ wrh,
                                             int s, int q, int wv) {
  const int sw = s & 7;
  u32 hpk[2];
#pragma unroll
  for (int p = 0; p < 2; ++p) {
    const floatx2 iv = {acc[0][2 * p], acc[0][2 * p + 1]};
    const floatx2 fv = {acc[1][2 * p], acc[1][2 * p + 1]};
    const floatx2 gv = {acc[2][2 * p], acc[2][2 * p + 1]};
    const floatx2 ov = {acc[3][2 * p], acc[3][2 * p + 1]};
    const floatx2 ei = exp2v(iv * -L2E);
    const floatx2 ef = exp2v(fv * -L2E);
    const floatx2 eg = exp2v(gv * (2.0f * L2E));
    const floatx2 eo = exp2v(ov * -L2E);
    const floatx2 A = ei + 1.0f;   // 1/sig(i)
    const floatx2 F = ef + 1.0f;   // 1/sig(f)
    const floatx2 Bg = eg + 1.0f;  // tanh(g) = (eg-1)/Bg
    const floatx2 P = A * Bg;
    const floatx2 num = c2[p] * P + (eg - 1.0f) * F;
    const floatx2 cn = num * rcp2(F * P);
    c2[p] = cn;
    const floatx2 ec = exp2v(cn * (2.0f * L2E));
    const floatx2 h = (ec - 1.0f) * rcp2((eo + 1.0f) * (ec + 1.0f));
    hpk[p] = (u32)f2bf(h.x) | ((u32)f2bf(h.y) << 16);
  }
  *(u32x2*)(wrh + s * 64 + (((wv * 2 + (q >> 1)) ^ sw) * 8) + (q & 1) * 4) =
      u32x2{hpk[0], hpk[1]};
}

// One cell step for this wave's 16-gate slice x 32 samples (encoder + dec step 0).
__device__ __forceinline__ void cell_step(const u16* __restrict__ rdh,
                                          const u16* __restrict__ rdx,
                                          u16* __restrict__ wrh,
                                          const short8 (&afh)[4][2],
                                          const short8 (&afx)[4][2],
                                          const float* __restrict__ biasrow,
                                          floatx2 (&c)[2][2],
                                          int q, int l16, int wv, int u0) {
#pragma unroll
  for (int n = 0; n < 2; ++n) {
    const int s = n * 16 + l16;
    const int sw = s & 7;
    const u16* hr = rdh + s * 64;
    const u16* xr = rdx + s * 64;
    const short8 hb0 = *(const short8*)(hr + ((q ^ sw) * 8));
    const short8 hb1 = *(const short8*)(hr + (((q + 4) ^ sw) * 8));
    const short8 xb0 = *(const short8*)(xr + ((q ^ sw) * 8));
    const short8 xb1 = *(const short8*)(xr + (((q + 4) ^ sw) * 8));
    floatx4 acc[4];
#pragma unroll
    for (int t = 0; t < 4; ++t) {
      const floatx4 bias = *(const floatx4*)(biasrow + t * 64 + u0 + q * 4);
      acc[t] = mfma_bf(afh[t][0], hb0, bias);
    }
#pragma unroll
    for (int t = 0; t < 4; ++t) acc[t] = mfma_bf(afx[t][0], xb0, acc[t]);
#pragma unroll
    for (int t = 0; t < 4; ++t) acc[t] = mfma_bf(afh[t][1], hb1, acc[t]);
#pragma unroll
    for (int t = 0; t < 4; ++t) acc[t] = mfma_bf(afx[t][1], xb1, acc[t]);
    nonlin_store(acc, c[n], wrh, s, q, wv);
  }
}

// Folded decoder step (j>=1): gates = h @ W_eff^T + b_eff (K=64, 16 MFMAs).
// rel_{j-1} = h_j @ h2p^T + pb is emitted via TWO extra MFMAs on the idle
// matrix pipe (afp rows 0/1 = h2p rows): wave 0 covers samples 0..15 (n=0),
// wave 1 covers 16..31 (n=1) -- no redundant VALU dot, no cross-lane reduce.
// rel goes to LDS (relS) so no global store / vmcnt drain inside the loop.
__device__ __forceinline__ void dec_step_folded(
    const u16* __restrict__ rdh, u16* __restrict__ wrh,
    const short8 (&af)[4][2], const short8 (&afp)[2],
    const float* __restrict__ biasrow, float b2p0, float b2p1,
    float* __restrict__ relrow,
    floatx2 (&c)[2][2], int q, int l16, int wv, int u0) {
  short8 hb0[2], hb1[2];
#pragma unroll
  for (int n = 0; n < 2; ++n) {
    const int s = n * 16 + l16, sw = s & 7;
    const u16* hr = rdh + s * 64;
    hb0[n] = *(const short8*)(hr + ((q ^ sw) * 8));
    hb1[n] = *(const short8*)(hr + (((q + 4) ^ sw) * 8));
  }
  floatx4 acc[2][4];
#pragma unroll
  for (int t = 0; t < 4; ++t) {
    const floatx4 bias = *(const floatx4*)(biasrow + t * 64 + u0 + q * 4);
    acc[0][t] = mfma_bf(af[t][0], hb0[0], bias);
    acc[1][t] = mfma_bf(af[t][0], hb0[1], bias);
  }
#pragma unroll
  for (int t = 0; t < 4; ++t) {
    acc[0][t] = mfma_bf(af[t][1], hb1[0], acc[0][t]);
    acc[1][t] = mfma_bf(af[t][1], hb1[1], acc[1][t]);
  }
  if (wv < 2) {  // 2 MFMAs on the idle matrix pipe; rows 0,1 land in q==0 lanes
    const short8 ha = wv ? hb0[1] : hb0[0];
    const short8 hc = wv ? hb1[1] : hb1[0];
    floatx4 ar = mfma_bf(afp[0], ha, floatx4{0.f, 0.f, 0.f, 0.f});
    ar = mfma_bf(afp[1], hc, ar);
    if (q == 0)
      *(floatx2*)(relrow + (wv * 16 + l16) * 2) =
          floatx2{ar[0] + b2p0, ar[1] + b2p1};
  }
#pragma unroll
  for (int n = 0; n < 2; ++n)
    nonlin_store(acc[n], c[n], wrh, n * 16 + l16, q, wv);
}

// x[s][e] = bf16( rb@bf16(emb_w)^T + emb_b ); used by encoder + dec step 0 only.
__device__ __forceinline__ void xgen8(float rb0, float rb1,
                                      const float* __restrict__ ew0,
                                      const float* __restrict__ ew1,
                                      const float* __restrict__ eb,
                                      u16* __restrict__ xw, int s8, int p8) {
  short8 v;
#pragma unroll
  for (int j = 0; j < 8; ++j) {
    const int e = p8 * 8 + j;
    v[j] = (short)f2bf(rb0 * ew0[e] + (rb1 * ew1[e] + eb[e]));
  }
  *(short8*)(xw + swz(s8, p8)) = v;
}

// (256,3): 168 = 84 arch + 84 accum. MFMA-only data (A-frags, acc, afp) in
// accum half; VALU-touched state must fit 84 arch regs. Decoder steps 1..11:
// gates = h @ W_eff^T + b_eff (rank-2 fold of the x-path); rel via 2 MFMAs on
// waves 0/1 (NOT a 4x-redundant VALU dot -- that was Round 1's regression);
// rel staged in LDS, flushed coalesced at the end (no vmcnt drain at barriers).
__global__ void __launch_bounds__(NTHREADS, 3)
lstm_kernel(const float* __restrict__ obs_rel,
            const float* __restrict__ enc_emb_w, const float* __restrict__ enc_emb_b,
            const float* __restrict__ enc_w_ih, const float* __restrict__ enc_w_hh,
            const float* __restrict__ enc_b_ih, const float* __restrict__ enc_b_hh,
            const float* __restrict__ dec_emb_w, const float* __restrict__ dec_emb_b,
            const float* __restrict__ dec_w_ih, const float* __restrict__ dec_w_hh,
            const float* __restrict__ dec_b_ih, const float* __restrict__ dec_b_hh,
            const float* __restrict__ h2p_w, const float* __restrict__ h2p_b,
            float* __restrict__ out, int batch) {
  __shared__ __align__(16) u16 hS[2][TILE_B * 64];
  __shared__ __align__(16) u16 xS[2][TILE_B * 64];
  __shared__ __align__(16) float posS[OBS_LEN][TILE_B * 2];
  __shared__ __align__(16) float biasS[3][256];  // enc, dec, dec-folded (f32)
  __shared__ float ew0e[64], ew1e[64], ebe[64];
  __shared__ float ew0d[64], ew1d[64], ebd[64];
  __shared__ __align__(16) float aS0[256], aS1[256];   // A_r[g] rank-2 factors
  __shared__ __align__(16) float hw0S[64], hw1S[64];   // h2p_w rows, f32
  __shared__ __align__(16) float relS[PRED_LEN][TILE_B * 2];  // rel staging

  const int tid = threadIdx.x;
  const int wv = tid >> 6, lane = tid & 63;
  const int q = lane >> 4, l16 = lane & 15;
  const int u0 = wv << 4;
  const int s8 = tid >> 3, p8 = tid & 7;
  const long S0 = (long)blockIdx.x * TILE_B;

  if (tid < 128) {  // stage all 8 encoder-step position rows (coalesced)
    const int t = tid >> 4, i = tid & 15;
    *(floatx4*)&posS[t][i * 4] =
        *(const floatx4*)(obs_rel + (long)t * batch * 2 + S0 * 2 + i * 4);
  }
  if (tid < 64) {  // emb tables: weights bf16-rounded (operands), biases f32
    ew0e[tid] = rndbf(enc_emb_w[tid * 2]);
    ew1e[tid] = rndbf(enc_emb_w[tid * 2 + 1]);
    ebe[tid] = enc_emb_b[tid];
    ew0d[tid] = rndbf(dec_emb_w[tid * 2]);
    ew1d[tid] = rndbf(dec_emb_w[tid * 2 + 1]);
    ebd[tid] = dec_emb_b[tid];
    hw0S[tid] = h2p_w[tid];        // f32: W_eff build; bf16-rounded into afp
    hw1S[tid] = h2p_w[64 + tid];
  }
  biasS[0][tid] = enc_b_ih[tid] + enc_b_hh[tid];
  {
    // Rank-2 fold factors for gate row g = tid (once per block, f32):
    // A_r[g] = sum_e W_ih[g,e]*emb_w[e,r];  B0[g] = sum_e W_ih[g,e]*emb_b[e]
    float A0 = 0.f, A1 = 0.f, B0 = 0.f;
    const float* wr = dec_w_ih + tid * 64;
#pragma unroll
    for (int e4 = 0; e4 < 16; ++e4) {
      const floatx4 w = *(const floatx4*)(wr + e4 * 4);
      const floatx4 m0 = *(const floatx4*)(dec_emb_w + e4 * 8);      // e0,e1 pairs
      const floatx4 m1 = *(const floatx4*)(dec_emb_w + e4 * 8 + 4);  // e2,e3 pairs
      const floatx4 bb = *(const floatx4*)(dec_emb_b + e4 * 4);
      A0 += w[0] * m0[0] + w[1] * m0[2] + w[2] * m1[0] + w[3] * m1[2];
      A1 += w[0] * m0[1] + w[1] * m0[3] + w[2] * m1[1] + w[3] * m1[3];
      B0 += w[0] * bb[0] + w[1] * bb[1] + w[2] * bb[2] + w[3] * bb[3];
    }
    aS0[tid] = A0;
    aS1[tid] = A1;
    const float db = dec_b_ih[tid] + dec_b_hh[tid];
    biasS[1][tid] = db;  // dec step 0 (unfolded)
    biasS[2][tid] = db + B0 + A0 * h2p_b[0] + A1 * h2p_b[1];  // folded steps
  }
  for (int i = tid; i < TILE_B * 64 / 2; i += NTHREADS) ((u32*)&hS[0][0])[i] = 0;

  short8 afh[4][2], afx[4][2];
  floatx2 c[2][2];
  load_afrags(enc_w_hh, afh, u0, q, l16);
  load_afrags(enc_w_ih, afx, u0, q, l16);
  c[0][0] = c[0][1] = c[1][0] = c[1][1] = floatx2{0.f, 0.f};
  const float b2p0 = h2p_b[0], b2p1 = h2p_b[1];
  __syncthreads();  // posS + tables + bias + fold factors + h0 visible
  {
    const floatx2 rr = *(const floatx2*)(&posS[0][s8 * 2]);
    xgen8(rndbf(rr.x), rndbf(rr.y), ew0e, ew1e, ebe, xS[0], s8, p8);
  }
  __syncthreads();  // x(0) visible

  int pb = 0;
#pragma unroll 1
  for (int t = 0; t < OBS_LEN; ++t) {
    // produce x(t+1) into the other buffer (h-independent, overlaps MFMA);
    // t==7 produces the decoder step-0 input with dec tables into xS[0]
    const int tn = t + 1;
    const floatx2 rr = *(const floatx2*)(&posS[(tn < 8) ? tn : 7][s8 * 2]);
    if (tn < 8)
      xgen8(rndbf(rr.x), rndbf(rr.y), ew0e, ew1e, ebe, xS[tn & 1], s8, p8);
    else
      xgen8(rndbf(rr.x), rndbf(rr.y), ew0d, ew1d, ebd, xS[0], s8, p8);
    cell_step(hS[pb], xS[t & 1], hS[pb ^ 1], afh, afx, &biasS[0][0], c,
              q, l16, wv, u0);
    __syncthreads();
    pb ^= 1;
  }

  // ---- decoder step 0 (x from last_pos, unfolded), c reset to 0
  load_afrags(dec_w_hh, afh, u0, q, l16);
  load_afrags(dec_w_ih, afx, u0, q, l16);
  c[0][0] = c[0][1] = c[1][0] = c[1][1] = floatx2{0.f, 0.f};
  cell_step(hS[pb], xS[0], hS[pb ^ 1], afh, afx, &biasS[1][0], c,
            q, l16, wv, u0);
  // rebuild afh as W_eff fragments (afx is dead from here on)
  load_afrags_eff(dec_w_hh, aS0, aS1, hw0S, hw1S, afh, u0, q, l16);
  // rel A-fragment: rows 0/1 = h2p rows (bf16), rows 2..15 = 0
  short8 afp[2];
#pragma unroll
  for (int kf = 0; kf < 2; ++kf) {
    const int kb = kf * 32 + q * 8;
    short8 a;
#pragma unroll
    for (int j = 0; j < 4; ++j) {
      const float r0 = (l16 == 0) ? hw0S[kb + j] : (l16 == 1) ? hw1S[kb + j] : 0.f;
      const float r1 =
          (l16 == 0) ? hw0S[kb + 4 + j] : (l16 == 1) ? hw1S[kb + 4 + j] : 0.f;
      a[j] = (short)f2bf(r0);
      a[j + 4] = (short)f2bf(r1);
    }
    afp[kf] = a;
  }
  __syncthreads();
  pb ^= 1;

  // ---- folded decoder steps 1..11: one barrier each; rel_{j-1} via MFMA
#pragma unroll 1
  for (int j = 1; j < PRED_LEN; ++j) {
    dec_step_folded(hS[pb], hS[pb ^ 1], afh, afp, &biasS[2][0], b2p0, b2p1,
                    &relS[j - 1][0], c, q, l16, wv, u0);
    __syncthreads();  // h_{j+1} ready; hS[pb] reads done before next overwrite
    pb ^= 1;
  }

  // ---- trailing output: rel_pos[11] from h_12 (2 MFMAs on waves 0/1)
  if (wv < 2) {
    const int s = wv * 16 + l16, sw = s & 7;
    const u16* hr = hS[pb] + s * 64;
    const short8 ha = *(const short8*)(hr + ((q ^ sw) * 8));
    const short8 hc = *(const short8*)(hr + (((q + 4) ^ sw) * 8));
    floatx4 ar = mfma_bf(afp[0], ha, floatx4{0.f, 0.f, 0.f, 0.f});
    ar = mfma_bf(afp[1], hc, ar);
    if (q == 0)
      *(floatx2*)(&relS[PRED_LEN - 1][s * 2]) =
          floatx2{ar[0] + b2p0, ar[1] + b2p1};
  }
  __syncthreads();

  // ---- flush relS -> out, fully coalesced (3 f32/thread)
#pragma unroll
  for (int r = 0; r < 3; ++r) {
    const int f = tid + r * 256;          // 0..767 = 12 rows x 64 f32
    const int j = f >> 6, e = f & 63;
    out[(long)j * batch * 2 + S0 * 2 + e] = ((const float*)relS)[f];
  }
}

extern "C" void kernel_launch(void* const* d_in, const int* in_sizes, int n_in,
                              void* d_out, int out_size, void* d_ws, size_t ws_size,
                              hipStream_t stream) {
  const float* obs_rel = (const float*)d_in[1];
  const int batch = in_sizes[1] / (OBS_LEN * 2);  // 65536

  const int blocks = batch / TILE_B;  // 2048
  hipLaunchKernelGGL(lstm_kernel, dim3(blocks), dim3(NTHREADS), 0, stream,
                     obs_rel,
                     (const float*)d_in[2], (const float*)d_in[3],
                     (const float*)d_in[4], (const float*)d_in[5],
                     (const float*)d_in[6], (const float*)d_in[7],
                     (const float*)d_in[8], (const float*)d_in[9],
                     (const float*)d_in[10], (const float*)d_in[11],
                     (const float*)d_in[12], (const float*)d_in[13],
                     (const float*)d_in[14], (const float*)d_in[15],
                     (float*)d_out, batch);
}

// Round 4
// 213.993 us; speedup vs baseline: 1.0888x; 1.0212x over previous
//
#include <hip/hip_runtime.h>

#define OBS_LEN 8
#define PRED_LEN 12
#define TILE_B 32
#define NTHREADS 256

typedef __attribute__((ext_vector_type(8))) short short8;  // 8 bf16
typedef __attribute__((ext_vector_type(4))) float floatx4;
typedef __attribute__((ext_vector_type(2))) float floatx2;
typedef __attribute__((ext_vector_type(2))) unsigned int u32x2;
typedef unsigned short u16;
typedef unsigned int u32;

#define L2E 1.442695040888963f

__device__ __forceinline__ u16 f2bf(float f) {
  __bf16 b = (__bf16)f;
  return __builtin_bit_cast(u16, b);
}
__device__ __forceinline__ float bf2f(u16 h) {
  return __builtin_bit_cast(float, ((u32)h) << 16);
}
__device__ __forceinline__ float rndbf(float f) { return (float)(__bf16)f; }

#if __has_builtin(__builtin_amdgcn_exp2f)
__device__ __forceinline__ float fexp2_(float x) { return __builtin_amdgcn_exp2f(x); }
#else
__device__ __forceinline__ float fexp2_(float x) { return exp2f(x); }
#endif
__device__ __forceinline__ floatx2 exp2v(floatx2 x) {
  floatx2 r;
  r.x = fexp2_(x.x);
  r.y = fexp2_(x.y);
  return r;
}
#if __has_builtin(__builtin_amdgcn_rcpf)
__device__ __forceinline__ floatx2 rcp2(floatx2 x) {  // raw v_rcp ~1ulp
  floatx2 r;
  r.x = __builtin_amdgcn_rcpf(x.x);
  r.y = __builtin_amdgcn_rcpf(x.y);
  return r;
}
#else
__device__ __forceinline__ floatx2 rcp2(floatx2 x) {
  return floatx2{1.0f / x.x, 1.0f / x.y};
}
#endif

__device__ __forceinline__ floatx4 mfma_bf(short8 a, short8 b, floatx4 c) {
  return __builtin_amdgcn_mfma_f32_16x16x32_bf16(a, b, c, 0, 0, 0);
}

// A-operand fragments (A[m=lane&15][k=quad*8+j]) for this wave's 4 gate tiles
// (gate = t*64 + u0 + l16), weights rounded to bf16 = the ref's operand rounding.
__device__ __forceinline__ void load_afrags(const float* __restrict__ W,
                                            short8 (&af)[4][2],
                                            int u0, int q, int l16) {
#pragma unroll
  for (int t = 0; t < 4; ++t)
#pragma unroll
    for (int kf = 0; kf < 2; ++kf) {
      const float* src = W + (t * 64 + u0 + l16) * 64 + kf * 32 + q * 8;
      const floatx4 w0 = *(const floatx4*)src;
      const floatx4 w1 = *(const floatx4*)(src + 4);
      short8 a;
#pragma unroll
      for (int j = 0; j < 4; ++j) {
        a[j] = (short)f2bf(w0[j]);
        a[j + 4] = (short)f2bf(w1[j]);
      }
      af[t][kf] = a;
    }
}

// Folded decoder weights: W_eff[g,u] = W_hh[g,u] + A0[g]*h2p[0,u] + A1[g]*h2p[1,u]
// (rank-2 update, f32 math, ONE bf16 rounding at the end).
__device__ __forceinline__ void load_afrags_eff(const float* __restrict__ Whh,
                                                const float* __restrict__ aS0,
                                                const float* __restrict__ aS1,
                                                const float* __restrict__ hw0,
                                                const float* __restrict__ hw1,
                                                short8 (&af)[4][2],
                                                int u0, int q, int l16) {
#pragma unroll
  for (int t = 0; t < 4; ++t) {
    const int g = t * 64 + u0 + l16;
    const float a0 = aS0[g], a1 = aS1[g];
#pragma unroll
    for (int kf = 0; kf < 2; ++kf) {
      const int u = kf * 32 + q * 8;
      const float* src = Whh + g * 64 + u;
      const floatx4 w0 = *(const floatx4*)src;
      const floatx4 w1 = *(const floatx4*)(src + 4);
      const floatx4 p00 = *(const floatx4*)(hw0 + u);
      const floatx4 p01 = *(const floatx4*)(hw0 + u + 4);
      const floatx4 p10 = *(const floatx4*)(hw1 + u);
      const floatx4 p11 = *(const floatx4*)(hw1 + u + 4);
      short8 a;
#pragma unroll
      for (int j = 0; j < 4; ++j) {
        a[j] = (short)f2bf(w0[j] + a0 * p00[j] + a1 * p10[j]);
        a[j + 4] = (short)f2bf(w1[j] + a0 * p01[j] + a1 * p11[j]);
      }
      af[t][kf] = a;
    }
  }
}

// Rank-2 input fold for gate row g: A_r[g] = sum_e W_ih[g,e]*emb_w[e,r],
// B0[g] = sum_e W_ih[g,e]*emb_b[e]. Collapses the whole x-path (x is a
// linear image of the 2-dim input) into 2 scalars/gate + bias.
__device__ __forceinline__ void fold_rank2(const float* __restrict__ wr,
                                           const float* __restrict__ emb_w,
                                           const float* __restrict__ emb_b,
                                           float& A0, float& A1, float& B0) {
  A0 = A1 = B0 = 0.f;
#pragma unroll
  for (int e4 = 0; e4 < 16; ++e4) {
    const floatx4 w = *(const floatx4*)(wr + e4 * 4);
    const floatx4 m0 = *(const floatx4*)(emb_w + e4 * 8);      // e0,e1 pairs
    const floatx4 m1 = *(const floatx4*)(emb_w + e4 * 8 + 4);  // e2,e3 pairs
    const floatx4 bb = *(const floatx4*)(emb_b + e4 * 4);
    A0 += w[0] * m0[0] + w[1] * m0[2] + w[2] * m1[0] + w[3] * m1[2];
    A1 += w[0] * m0[1] + w[1] * m0[3] + w[2] * m1[1] + w[3] * m1[3];
    B0 += w[0] * bb[0] + w[1] * bb[1] + w[2] * bb[2] + w[3] * bb[3];
  }
}

// Pos-term A-fragment: column k=0 holds A0[g], k=1 holds A1[g], rest zero.
// Used as mfma(gf, posfrag, bias) -> adds p0*A0[g]+p1*A1[g] on the matrix pipe.
__device__ __forceinline__ void build_gfrag(const float* __restrict__ A0t,
                                            const float* __restrict__ A1t,
                                            short8 (&gf)[4],
                                            int u0, int q, int l16) {
#pragma unroll
  for (int t = 0; t < 4; ++t) {
    short8 a = short8{0, 0, 0, 0, 0, 0, 0, 0};
    if (q == 0) {
      const int g = t * 64 + u0 + l16;
      a[0] = (short)f2bf(A0t[g]);
      a[1] = (short)f2bf(A1t[g]);
    }
    gf[t] = a;
  }
}

// Gate nonlinearity + swizzled h write for one 16x16 tile (verbatim math from
// the proven kernel; c2 = running cell state for this n-tile).
__device__ __forceinline__ void nonlin_store(const floatx4 (&acc)[4],
                                             floatx2 (&c2)[2],
                                             u16* __restrict__ wrh,
                                             int s, int q, int wv) {
  const int sw = s & 7;
  u32 hpk[2];
#pragma unroll
  for (int p = 0; p < 2; ++p) {
    const floatx2 iv = {acc[0][2 * p], acc[0][2 * p + 1]};
    const floatx2 fv = {acc[1][2 * p], acc[1][2 * p + 1]};
    const floatx2 gv = {acc[2][2 * p], acc[2][2 * p + 1]};
    const floatx2 ov = {acc[3][2 * p], acc[3][2 * p + 1]};
    const floatx2 ei = exp2v(iv * -L2E);
    const floatx2 ef = exp2v(fv * -L2E);
    const floatx2 eg = exp2v(gv * (2.0f * L2E));
    const floatx2 eo = exp2v(ov * -L2E);
    const floatx2 A = ei + 1.0f;   // 1/sig(i)
    const floatx2 F = ef + 1.0f;   // 1/sig(f)
    const floatx2 Bg = eg + 1.0f;  // tanh(g) = (eg-1)/Bg
    const floatx2 P = A * Bg;
    const floatx2 num = c2[p] * P + (eg - 1.0f) * F;
    const floatx2 cn = num * rcp2(F * P);
    c2[p] = cn;
    const floatx2 ec = exp2v(cn * (2.0f * L2E));
    const floatx2 h = (ec - 1.0f) * rcp2((eo + 1.0f) * (ec + 1.0f));
    hpk[p] = (u32)f2bf(h.x) | ((u32)f2bf(h.y) << 16);
  }
  *(u32x2*)(wrh + s * 64 + (((wv * 2 + (q >> 1)) ^ sw) * 8) + (q & 1) * 4) =
      u32x2{hpk[0], hpk[1]};
}

// One fully-folded cell step: gates = h @ W_hh^T + (p0*A0 + p1*A1 + bias).
// Pos term via 1 extra MFMA per gate-group (zero-padded K) -- matrix pipe,
// independent of the h ds_reads so it issues first. 12 MFMAs per n-tile.
__device__ __forceinline__ void cell_step_fold(
    const u16* __restrict__ rdh, u16* __restrict__ wrh,
    const short8 (&afh)[4][2], const short8 (&gf)[4],
    const float* __restrict__ biasrow, const float* __restrict__ posrow,
    floatx2 (&c)[2][2], int q, int l16, int wv, int u0) {
#pragma unroll
  for (int n = 0; n < 2; ++n) {
    const int s = n * 16 + l16, sw = s & 7;
    const u16* hr = rdh + s * 64;
    const short8 hb0 = *(const short8*)(hr + ((q ^ sw) * 8));
    const short8 hb1 = *(const short8*)(hr + (((q + 4) ^ sw) * 8));
    const floatx2 pp = *(const floatx2*)(posrow + s * 2);
    short8 pf = short8{0, 0, 0, 0, 0, 0, 0, 0};
    if (q == 0) {
      pf[0] = (short)f2bf(pp.x);
      pf[1] = (short)f2bf(pp.y);
    }
    floatx4 acc[4];
#pragma unroll
    for (int t = 0; t < 4; ++t) {
      const floatx4 bias = *(const floatx4*)(biasrow + t * 64 + u0 + q * 4);
      acc[t] = mfma_bf(gf[t], pf, bias);  // pos term, no h dependence
    }
#pragma unroll
    for (int t = 0; t < 4; ++t) acc[t] = mfma_bf(afh[t][0], hb0, acc[t]);
#pragma unroll
    for (int t = 0; t < 4; ++t) acc[t] = mfma_bf(afh[t][1], hb1, acc[t]);
    nonlin_store(acc, c[n], wrh, s, q, wv);
  }
}

// Folded decoder step (j>=1): gates = h @ W_eff^T + b_eff (K=64, 8 MFMAs/n).
// n-loop SERIALIZED (acc[4] not acc[2][4]) to fit the (256,4) register budget;
// 4 blocks/CU TLP covers the ILP loss. rel_{j-1} via 2 MFMAs: wave n handles
// tile n when the loop reaches it. rel -> LDS (no vmcnt drain at barriers).
__device__ __forceinline__ void dec_step_folded(
    const u16* __restrict__ rdh, u16* __restrict__ wrh,
    const short8 (&af)[4][2], const short8 (&afp)[2],
    const float* __restrict__ biasrow, float b2p0, float b2p1,
    float* __restrict__ relrow,
    floatx2 (&c)[2][2], int q, int l16, int wv, int u0) {
#pragma unroll
  for (int n = 0; n < 2; ++n) {
    const int s = n * 16 + l16, sw = s & 7;
    const u16* hr = rdh + s * 64;
    const short8 hb0 = *(const short8*)(hr + ((q ^ sw) * 8));
    const short8 hb1 = *(const short8*)(hr + (((q + 4) ^ sw) * 8));
    floatx4 acc[4];
#pragma unroll
    for (int t = 0; t < 4; ++t) {
      const floatx4 bias = *(const floatx4*)(biasrow + t * 64 + u0 + q * 4);
      acc[t] = mfma_bf(af[t][0], hb0, bias);
    }
#pragma unroll
    for (int t = 0; t < 4; ++t) acc[t] = mfma_bf(af[t][1], hb1, acc[t]);
    if (wv == n) {  // 2 rel MFMAs on the idle matrix pipe; rows 0,1 -> q==0
      floatx4 ar = mfma_bf(afp[0], hb0, floatx4{0.f, 0.f, 0.f, 0.f});
      ar = mfma_bf(afp[1], hb1, ar);
      if (q == 0)
        *(floatx2*)(relrow + s * 2) = floatx2{ar[0] + b2p0, ar[1] + b2p1};
    }
    nonlin_store(acc, c[n], wrh, s, q, wv);
  }
}

// (256,4): 16 waves/CU, 4 blocks/CU, 128 VGPR/wave budget. Enabled by folding
// BOTH linear input paths: encoder x_t = lin(pos_t) and decoder x_j = lin(h_j)
// -> afx eliminated (-32 regs), xS eliminated (-8KB LDS), xgen8 gone. Every
// step is gates = h @ W^T + rank-2 term; pos term rides the matrix pipe.
__global__ void __launch_bounds__(NTHREADS, 4)
lstm_kernel(const float* __restrict__ obs_rel,
            const float* __restrict__ enc_emb_w, const float* __restrict__ enc_emb_b,
            const float* __restrict__ enc_w_ih, const float* __restrict__ enc_w_hh,
            const float* __restrict__ enc_b_ih, const float* __restrict__ enc_b_hh,
            const float* __restrict__ dec_emb_w, const float* __restrict__ dec_emb_b,
            const float* __restrict__ dec_w_ih, const float* __restrict__ dec_w_hh,
            const float* __restrict__ dec_b_ih, const float* __restrict__ dec_b_hh,
            const float* __restrict__ h2p_w, const float* __restrict__ h2p_b,
            float* __restrict__ out, int batch) {
  __shared__ __align__(16) u16 hS[2][TILE_B * 64];
  __shared__ __align__(16) float posS[OBS_LEN][TILE_B * 2];
  __shared__ __align__(16) float biasS[3][256];  // enc, dec0, dec-folded (f32)
  __shared__ __align__(16) float eA0[256], eA1[256];  // encoder rank-2 factors
  __shared__ __align__(16) float dA0[256], dA1[256];  // decoder rank-2 factors
  __shared__ __align__(16) float hw0S[64], hw1S[64];  // h2p_w rows, f32
  __shared__ __align__(16) float relS[PRED_LEN][TILE_B * 2];  // rel staging

  const int tid = threadIdx.x;
  const int wv = tid >> 6, lane = tid & 63;
  const int q = lane >> 4, l16 = lane & 15;
  const int u0 = wv << 4;
  const long S0 = (long)blockIdx.x * TILE_B;

  if (tid < 128) {  // stage all 8 encoder-step position rows (coalesced)
    const int t = tid >> 4, i = tid & 15;
    *(floatx4*)&posS[t][i * 4] =
        *(const floatx4*)(obs_rel + (long)t * batch * 2 + S0 * 2 + i * 4);
  }
  if (tid < 64) {
    hw0S[tid] = h2p_w[tid];        // f32: W_eff build + afp source
    hw1S[tid] = h2p_w[64 + tid];
  }
  {
    float A0, A1, B0;
    fold_rank2(enc_w_ih + tid * 64, enc_emb_w, enc_emb_b, A0, A1, B0);
    eA0[tid] = A0;
    eA1[tid] = A1;
    biasS[0][tid] = enc_b_ih[tid] + enc_b_hh[tid] + B0;
    fold_rank2(dec_w_ih + tid * 64, dec_emb_w, dec_emb_b, A0, A1, B0);
    dA0[tid] = A0;
    dA1[tid] = A1;
    const float db = dec_b_ih[tid] + dec_b_hh[tid] + B0;
    biasS[1][tid] = db;                                   // dec step 0
    biasS[2][tid] = db + A0 * h2p_b[0] + A1 * h2p_b[1];   // folded steps
  }
  for (int i = tid; i < TILE_B * 64 / 2; i += NTHREADS) ((u32*)&hS[0][0])[i] = 0;

  short8 afh[4][2], gf[4];
  floatx2 c[2][2];
  load_afrags(enc_w_hh, afh, u0, q, l16);
  c[0][0] = c[0][1] = c[1][0] = c[1][1] = floatx2{0.f, 0.f};
  const float b2p0 = h2p_b[0], b2p1 = h2p_b[1];
  __syncthreads();  // posS + tables + bias + fold factors + h0 visible
  build_gfrag(eA0, eA1, gf, u0, q, l16);

  int pb = 0;
#pragma unroll 1
  for (int t = 0; t < OBS_LEN; ++t) {
    cell_step_fold(hS[pb], hS[pb ^ 1], afh, gf, &biasS[0][0], &posS[t][0], c,
                   q, l16, wv, u0);
    __syncthreads();
    pb ^= 1;
  }

  // ---- decoder step 0: x0 = lin(pos7) folded with dec tables, c reset
  load_afrags(dec_w_hh, afh, u0, q, l16);
  build_gfrag(dA0, dA1, gf, u0, q, l16);
  c[0][0] = c[0][1] = c[1][0] = c[1][1] = floatx2{0.f, 0.f};
  cell_step_fold(hS[pb], hS[pb ^ 1], afh, gf, &biasS[1][0], &posS[7][0], c,
                 q, l16, wv, u0);
  // rebuild afh as W_eff fragments for the h-feedback fold
  load_afrags_eff(dec_w_hh, dA0, dA1, hw0S, hw1S, afh, u0, q, l16);
  // rel A-fragment: rows 0/1 = h2p rows (bf16), rows 2..15 = 0
  short8 afp[2];
#pragma unroll
  for (int kf = 0; kf < 2; ++kf) {
    const int kb = kf * 32 + q * 8;
    short8 a;
#pragma unroll
    for (int j = 0; j < 4; ++j) {
      const float r0 = (l16 == 0) ? hw0S[kb + j] : (l16 == 1) ? hw1S[kb + j] : 0.f;
      const float r1 =
          (l16 == 0) ? hw0S[kb + 4 + j] : (l16 == 1) ? hw1S[kb + 4 + j] : 0.f;
      a[j] = (short)f2bf(r0);
      a[j + 4] = (short)f2bf(r1);
    }
    afp[kf] = a;
  }
  __syncthreads();
  pb ^= 1;

  // ---- folded decoder steps 1..11: one barrier each; rel_{j-1} via MFMA
#pragma unroll 1
  for (int j = 1; j < PRED_LEN; ++j) {
    dec_step_folded(hS[pb], hS[pb ^ 1], afh, afp, &biasS[2][0], b2p0, b2p1,
                    &relS[j - 1][0], c, q, l16, wv, u0);
    __syncthreads();  // h_{j+1} ready; hS[pb] reads done before next overwrite
    pb ^= 1;
  }

  // ---- trailing output: rel_pos[11] from h_12 (2 MFMAs on waves 0/1)
  if (wv < 2) {
    const int s = wv * 16 + l16, sw = s & 7;
    const u16* hr = hS[pb] + s * 64;
    const short8 ha = *(const short8*)(hr + ((q ^ sw) * 8));
    const short8 hc = *(const short8*)(hr + (((q + 4) ^ sw) * 8));
    floatx4 ar = mfma_bf(afp[0], ha, floatx4{0.f, 0.f, 0.f, 0.f});
    ar = mfma_bf(afp[1], hc, ar);
    if (q == 0)
      *(floatx2*)(&relS[PRED_LEN - 1][s * 2]) =
          floatx2{ar[0] + b2p0, ar[1] + b2p1};
  }
  __syncthreads();

  // ---- flush relS -> out, fully coalesced (3 f32/thread)
#pragma unroll
  for (int r = 0; r < 3; ++r) {
    const int f = tid + r * 256;          // 0..767 = 12 rows x 64 f32
    const int j = f >> 6, e = f & 63;
    out[(long)j * batch * 2 + S0 * 2 + e] = ((const float*)relS)[f];
  }
}

extern "C" void kernel_launch(void* const* d_in, const int* in_sizes, int n_in,
                              void* d_out, int out_size, void* d_ws, size_t ws_size,
                              hipStream_t stream) {
  const float* obs_rel = (const float*)d_in[1];
  const int batch = in_sizes[1] / (OBS_LEN * 2);  // 65536

  const int blocks = batch / TILE_B;  // 2048
  hipLaunchKernelGGL(lstm_kernel, dim3(blocks), dim3(NTHREADS), 0, stream,
                     obs_rel,
                     (const float*)d_in[2], (const float*)d_in[3],
                     (const float*)d_in[4], (const float*)d_in[5],
                     (const float*)d_in[6], (const float*)d_in[7],
                     (const float*)d_in[8], (const float*)d_in[9],
                     (const float*)d_in[10], (const float*)d_in[11],
                     (const float*)d_in[12], (const float*)d_in[13],
                     (const float*)d_in[14], (const float*)d_in[15],
                     (float*)d_out, batch);
}